// Round 4
// baseline (267.312 us; speedup 1.0000x reference)
//
#include <hip/hip_runtime.h>
#include <hip/hip_bf16.h>
#include <cstdint>

#define T_TOK 8192
#define HID   1024
#define NE    9      // 8 routed experts + 1 shared
#define ISZ   512
#define RBASE 17408  // routed slot space: 16384 + 8*128 padding; shared rows at [RBASE, RBASE+8192)
#define NSLOT (RBASE + T_TOK)

#define BM 128
#define BN 128
#define BK 32

typedef unsigned short u16;
typedef unsigned int   u32;
typedef __attribute__((ext_vector_type(8))) short short8;
typedef __attribute__((ext_vector_type(4))) float f32x4;

__device__ __forceinline__ u16 f2bf(float f) {
  u32 u = __builtin_bit_cast(u32, f);
  return (u16)((u + 0x7fffu + ((u >> 16) & 1u)) >> 16);
}
__device__ __forceinline__ float bf2f(u16 v) {
  return __builtin_bit_cast(float, (u32)v << 16);
}

#define STAGE(gp, lp) __builtin_amdgcn_global_load_lds( \
    (__attribute__((address_space(1))) u32*)(gp),       \
    (__attribute__((address_space(3))) u32*)(lp), 16, 0, 0)

// ---------------- weight conversions ----------------
// w_experts_gate_up [8][1024][1024] + w_shared_gate_up [1024][1024]
// -> dst [9][1024(colp)][1024(h)]  (transposed, gate/up interleaved per 16 cols)
__global__ void k_cvt_wgup(const float* __restrict__ wexp, const float* __restrict__ wsh,
                           u16* __restrict__ dst) {
  __shared__ float tile[32][33];
  const int e = blockIdx.z;
  const float* src = (e < 8) ? (wexp + (size_t)e * HID * 1024) : wsh;
  const int c0 = blockIdx.x * 32, h0 = blockIdx.y * 32;
  const int tx = threadIdx.x, ty = threadIdx.y;
  for (int i = ty; i < 32; i += 8)
    tile[i][tx] = src[(size_t)(h0 + i) * 1024 + c0 + tx];   // tile[h_loc][c_loc]
  __syncthreads();
  for (int j = ty; j < 32; j += 8) {
    int c = c0 + j;
    int i = (c < 512) ? c : (c - 512);
    int colp = ((i >> 4) * 32) + ((c < 512) ? 0 : 16) + (i & 15);
    dst[((size_t)e * 1024 + colp) * HID + h0 + tx] = f2bf(tile[tx][j]);
  }
}

// w_experts_down [8][512][1024] + w_shared_down [512][1024]
// -> dst [9][1024(h_out)][512(i)]  (transposed)
__global__ void k_cvt_wdown(const float* __restrict__ wexp, const float* __restrict__ wsh,
                            u16* __restrict__ dst) {
  __shared__ float tile[32][33];
  const int e = blockIdx.z;
  const float* src = (e < 8) ? (wexp + (size_t)e * ISZ * HID) : wsh;
  const int h0 = blockIdx.x * 32, i0 = blockIdx.y * 32;
  const int tx = threadIdx.x, ty = threadIdx.y;
  for (int a = ty; a < 32; a += 8)
    tile[a][tx] = src[(size_t)(i0 + a) * HID + h0 + tx];    // tile[i_loc][h_loc]
  __syncthreads();
  for (int j = ty; j < 32; j += 8)
    dst[((size_t)e * HID + h0 + j) * ISZ + i0 + tx] = f2bf(tile[tx][j]);
}

// ---------------- router (fused x->bf16 conversion), no atomics ----------------
__global__ __launch_bounds__(256) void k_router(
    const float* __restrict__ x, const float* __restrict__ wg,
    u16* __restrict__ xb, int* __restrict__ eidx, float2* __restrict__ wts) {
  const int t = blockIdx.x * 4 + (threadIdx.x >> 6);
  const int l = threadIdx.x & 63;
  float a[8] = {0, 0, 0, 0, 0, 0, 0, 0};
  const float* xr = x + (size_t)t * HID;
  u16* xbr = xb + (size_t)t * HID;
#pragma unroll
  for (int j = 0; j < HID / 64; ++j) {
    const int h = j * 64 + l;
    const float xv = xr[h];
    xbr[h] = f2bf(xv);
    const float4 w0 = *(const float4*)&wg[h * 8];
    const float4 w1 = *(const float4*)&wg[h * 8 + 4];
    a[0] += xv * w0.x; a[1] += xv * w0.y; a[2] += xv * w0.z; a[3] += xv * w0.w;
    a[4] += xv * w1.x; a[5] += xv * w1.y; a[6] += xv * w1.z; a[7] += xv * w1.w;
  }
#pragma unroll
  for (int off = 32; off >= 1; off >>= 1) {
#pragma unroll
    for (int e2 = 0; e2 < 8; ++e2) a[e2] += __shfl_xor(a[e2], off);
  }
  if (l == 0) {
    int ia = 0;
#pragma unroll
    for (int e2 = 1; e2 < 8; ++e2) if (a[e2] > a[ia]) ia = e2;
    int ib = (ia == 0) ? 1 : 0;
#pragma unroll
    for (int e2 = 0; e2 < 8; ++e2) if (e2 != ia && a[e2] > a[ib]) ib = e2;
    float wa = 1.f / (1.f + expf(a[ib] - a[ia]));  // renormalized softmax top-2
    eidx[t] = ia | (ib << 8);
    wts[t] = make_float2(wa, 1.f - wa);
  }
}

// ---------------- deterministic counting scatter ----------------
// 1 block, 8 waves; wave e owns expert e. Token-ordered buckets, 128-aligned segments.
__global__ __launch_bounds__(512) void k_scatter(
    const int* __restrict__ eidx, const float2* __restrict__ wts,
    int* __restrict__ btok, float* __restrict__ bw, int* __restrict__ slotmap,
    int* __restrict__ seg, int* __restrict__ segcnt) {
  __shared__ int cnt_s[8];
  __shared__ int goff_s[9];
  const int e = threadIdx.x >> 6;
  const int l = threadIdx.x & 63;

  int c1 = 0;
  for (int c = 0; c < T_TOK / 64; ++c) {
    int v = eidx[c * 64 + l];
    c1 += __popcll(__ballot((v & 255) == e)) + __popcll(__ballot(((v >> 8) & 255) == e));
  }
  if (l == 0) cnt_s[e] = c1;
  __syncthreads();
  if (threadIdx.x == 0) {
    int off = 0;
    for (int k = 0; k < 8; ++k) { goff_s[k] = off; off += (cnt_s[k] + 127) & ~127; }
    goff_s[8] = off;
  }
  __syncthreads();
  const int base0 = goff_s[e];
  const int cnt_e = cnt_s[e];
  const unsigned long long below = (l == 63) ? ~0ull >> 1 : ((1ull << l) - 1);

  int base = base0;
  for (int c = 0; c < T_TOK / 64; ++c) {
    const int t = c * 64 + l;
    const int v = eidx[t];
    const float2 wv = wts[t];
    const unsigned long long ma = __ballot((v & 255) == e);
    const unsigned long long mb = __ballot(((v >> 8) & 255) == e);
    if ((v & 255) == e) {
      int s = base + __popcll(ma & below);
      btok[s] = t; bw[s] = wv.x; slotmap[2 * t] = s;
    }
    if (((v >> 8) & 255) == e) {
      int s = base + __popcll(ma) + __popcll(mb & below);
      btok[s] = t; bw[s] = wv.y; slotmap[2 * t + 1] = s;
    }
    base += __popcll(ma) + __popcll(mb);
  }
  for (int p = cnt_e + l; p < ((cnt_e + 127) & ~127); p += 64) {
    btok[base0 + p] = 0; bw[base0 + p] = 0.f;
  }
  if (threadIdx.x < 9) seg[threadIdx.x] = goff_s[threadIdx.x];
  if (threadIdx.x < 8) segcnt[threadIdx.x] = cnt_s[threadIdx.x];
}

// ---------------- segment lookup ----------------
__device__ __forceinline__ bool seg_lookup(const int* __restrict__ seg,
                                           const int* __restrict__ segcnt,
                                           int brow, int& e) {
  if (brow >= RBASE) { e = 8; return true; }
  if (brow >= seg[8]) return false;
  e = 0;
#pragma unroll
  for (int k = 1; k < 8; ++k) if (brow >= seg[k]) e = k;
  return brow < seg[e] + segcnt[e];
}

// ---------------- GEMM1: act[slot] = silu(g)*u * w  (A gathered by token) -------
// 1-D grid, bcol = bid&7 -> XCD i owns column-block i (B slice L2-resident).
__global__ __launch_bounds__(256) void k_gemm_gu(
    const u16* __restrict__ xb,     // [T][H] bf16
    const u16* __restrict__ wgupT,  // [NE][1024][H] bf16 (B^T, interleaved cols)
    const int* __restrict__ seg, const int* __restrict__ segcnt,
    const int* __restrict__ btok, const float* __restrict__ bw,
    u16* __restrict__ act)          // [NSLOT][ISZ] bf16 (pre-scaled)
{
  const int bid = blockIdx.x;
  const int bcol_blk = bid & 7;
  const int brow = (bid >> 3) * BM;
  int e;
  if (!seg_lookup(seg, segcnt, brow, e)) return;

  __shared__ __align__(16) u16 As[BM * BK];
  __shared__ __align__(16) u16 Bs[BN * BK];
  __shared__ float cws[BM];

  const int tid = threadIdx.x;
  const int w = tid >> 6, l = tid & 63;
  const int bcol = bcol_blk * BN;

  if (tid < BM) cws[tid] = (e < 8) ? bw[brow + tid] : 1.f;

  const int sub = l >> 2;        // row within 16-row chunk
  const int kc  = (l & 3) * 8;   // k element offset

  const int gs0 = brow + (w * 2 + 0) * 16 + sub;
  const int gs1 = brow + (w * 2 + 1) * 16 + sub;
  const int t0 = (e < 8) ? btok[gs0] : (gs0 - RBASE);
  const int t1 = (e < 8) ? btok[gs1] : (gs1 - RBASE);

  const u16* ga0 = xb + (size_t)t0 * HID + kc;
  const u16* ga1 = xb + (size_t)t1 * HID + kc;
  const u16* gb0 = wgupT + ((size_t)e * 1024 + bcol + (w * 2 + 0) * 16 + sub) * HID + kc;
  const u16* gb1 = wgupT + ((size_t)e * 1024 + bcol + (w * 2 + 1) * 16 + sub) * HID + kc;

  u16* la0 = &As[(w * 2 + 0) * 16 * BK];
  u16* la1 = &As[(w * 2 + 1) * 16 * BK];
  u16* lb0 = &Bs[(w * 2 + 0) * 16 * BK];
  u16* lb1 = &Bs[(w * 2 + 1) * 16 * BK];

  const int wm = w >> 1, wn = w & 1;
  const int fr = l & 15, fg = l >> 4;

  f32x4 acc[4][4];
#pragma unroll
  for (int m = 0; m < 4; ++m)
#pragma unroll
    for (int n = 0; n < 4; ++n) acc[m][n] = (f32x4){0.f, 0.f, 0.f, 0.f};

  for (int kt = 0; kt < HID / BK; ++kt) {
    const int ko = kt * BK;
    STAGE(ga0 + ko, la0);
    STAGE(ga1 + ko, la1);
    STAGE(gb0 + ko, lb0);
    STAGE(gb1 + ko, lb1);
    __syncthreads();
    short8 af[4], bfr[4];
#pragma unroll
    for (int m = 0; m < 4; ++m)
      af[m] = *(const short8*)&As[(wm * 64 + m * 16 + fr) * BK + fg * 8];
#pragma unroll
    for (int n = 0; n < 4; ++n)
      bfr[n] = *(const short8*)&Bs[(wn * 64 + n * 16 + fr) * BK + fg * 8];
#pragma unroll
    for (int m = 0; m < 4; ++m)
#pragma unroll
      for (int n = 0; n < 4; ++n)
        acc[m][n] = __builtin_amdgcn_mfma_f32_16x16x32_bf16(af[m], bfr[n], acc[m][n], 0, 0, 0);
    __syncthreads();
  }

#pragma unroll
  for (int m = 0; m < 4; ++m) {
#pragma unroll
    for (int p = 0; p < 2; ++p) {
      f32x4 g = acc[m][2 * p], u = acc[m][2 * p + 1];
      const int col = (bcol_blk * 4 + wn * 2 + p) * 16 + fr;
#pragma unroll
      for (int r = 0; r < 4; ++r) {
        const int row_l = wm * 64 + m * 16 + fg * 4 + r;
        float gate = g[r], u2 = u[r];
        float s = gate / (1.f + expf(-gate));
        act[(size_t)(brow + row_l) * ISZ + col] = f2bf(s * u2 * cws[row_l]);
      }
    }
  }
}

// ---------------- GEMM2 (unified routed+shared): tmp[slot] = act[slot] @ wdT[e] --
__global__ __launch_bounds__(256) void k_gemm_down(
    const u16* __restrict__ act, const u16* __restrict__ wdT,
    const int* __restrict__ seg, const int* __restrict__ segcnt,
    u16* __restrict__ tmp) {
  const int bid = blockIdx.x;
  const int bcol_blk = bid & 7;
  const int brow = (bid >> 3) * BM;
  int e;
  if (!seg_lookup(seg, segcnt, brow, e)) return;
  const int bcol = bcol_blk * BN;

  __shared__ __align__(16) u16 As[BM * BK];
  __shared__ __align__(16) u16 Bs[BN * BK];

  const int tid = threadIdx.x;
  const int w = tid >> 6, l = tid & 63;
  const int sub = l >> 2;
  const int kc  = (l & 3) * 8;

  const u16* pa0 = act + (size_t)(brow + (w * 2 + 0) * 16 + sub) * ISZ + kc;
  const u16* pa1 = act + (size_t)(brow + (w * 2 + 1) * 16 + sub) * ISZ + kc;
  const u16* pb0 = wdT + ((size_t)e * HID + bcol + (w * 2 + 0) * 16 + sub) * ISZ + kc;
  const u16* pb1 = wdT + ((size_t)e * HID + bcol + (w * 2 + 1) * 16 + sub) * ISZ + kc;

  u16* la0 = &As[(w * 2 + 0) * 16 * BK];
  u16* la1 = &As[(w * 2 + 1) * 16 * BK];
  u16* lb0 = &Bs[(w * 2 + 0) * 16 * BK];
  u16* lb1 = &Bs[(w * 2 + 1) * 16 * BK];

  const int wm = w >> 1, wn = w & 1;
  const int fr = l & 15, fg = l >> 4;

  f32x4 acc[4][4];
#pragma unroll
  for (int m = 0; m < 4; ++m)
#pragma unroll
    for (int n = 0; n < 4; ++n) acc[m][n] = (f32x4){0.f, 0.f, 0.f, 0.f};

  for (int kt = 0; kt < ISZ / BK; ++kt) {   // 16 iters
    const int ko = kt * BK;
    STAGE(pa0 + ko, la0);
    STAGE(pa1 + ko, la1);
    STAGE(pb0 + ko, lb0);
    STAGE(pb1 + ko, lb1);
    __syncthreads();
    short8 af[4], bfr[4];
#pragma unroll
    for (int m = 0; m < 4; ++m)
      af[m] = *(const short8*)&As[(wm * 64 + m * 16 + fr) * BK + fg * 8];
#pragma unroll
    for (int n = 0; n < 4; ++n)
      bfr[n] = *(const short8*)&Bs[(wn * 64 + n * 16 + fr) * BK + fg * 8];
#pragma unroll
    for (int m = 0; m < 4; ++m)
#pragma unroll
      for (int n = 0; n < 4; ++n)
        acc[m][n] = __builtin_amdgcn_mfma_f32_16x16x32_bf16(af[m], bfr[n], acc[m][n], 0, 0, 0);
    __syncthreads();
  }

#pragma unroll
  for (int m = 0; m < 4; ++m) {
#pragma unroll
    for (int r = 0; r < 4; ++r) {
      const int row = brow + wm * 64 + m * 16 + fg * 4 + r;
#pragma unroll
      for (int n = 0; n < 4; ++n) {
        const int col = bcol + wn * 64 + n * 16 + fr;
        tmp[(size_t)row * HID + col] = f2bf(acc[m][n][r]);
      }
    }
  }
}

// ---------------- combine: out[t] = tmp[sh] + tmp[s0] + tmp[s1]  (pure write) ----
__global__ __launch_bounds__(256) void k_combine(
    const u16* __restrict__ tmp, const int* __restrict__ slotmap,
    float* __restrict__ out) {
  const int idx = blockIdx.x * 256 + threadIdx.x;
  const int t = idx >> 7;
  const int c = (idx & 127) << 3;
  const int s0 = slotmap[2 * t], s1 = slotmap[2 * t + 1];
  const short8 a = *(const short8*)(tmp + (size_t)s0 * HID + c);
  const short8 b = *(const short8*)(tmp + (size_t)s1 * HID + c);
  const short8 s = *(const short8*)(tmp + (size_t)(RBASE + t) * HID + c);
  float r[8];
#pragma unroll
  for (int j = 0; j < 8; ++j)
    r[j] = bf2f((u16)s[j]) + bf2f((u16)a[j]) + bf2f((u16)b[j]);
  float* po = out + (size_t)t * HID + c;
  *(float4*)po       = make_float4(r[0], r[1], r[2], r[3]);
  *(float4*)(po + 4) = make_float4(r[4], r[5], r[6], r[7]);
}

// ---------------- launch ----------------
extern "C" void kernel_launch(void* const* d_in, const int* in_sizes, int n_in,
                              void* d_out, int out_size, void* d_ws, size_t ws_size,
                              hipStream_t stream) {
  const float* x   = (const float*)d_in[0];
  const float* wg  = (const float*)d_in[1];
  const float* wgu = (const float*)d_in[2];
  const float* wdn = (const float*)d_in[3];
  const float* wsg = (const float*)d_in[4];
  const float* wsd = (const float*)d_in[5];
  float* out = (float*)d_out;

  char* ws = (char*)d_ws;
  u16* xb    = (u16*)ws;  ws += (size_t)T_TOK * HID * 2;
  u16* wgupT = (u16*)ws;  ws += (size_t)NE * 1024 * HID * 2;
  u16* wdT   = (u16*)ws;  ws += (size_t)NE * HID * ISZ * 2;
  u16* actb  = (u16*)ws;  ws += (size_t)NSLOT * ISZ * 2;
  u16* tmp   = (u16*)ws;  ws += (size_t)NSLOT * HID * 2;
  int* eidx  = (int*)ws;  ws += (size_t)T_TOK * 4;
  float2* wt = (float2*)ws; ws += (size_t)T_TOK * 8;
  int* btok  = (int*)ws;  ws += (size_t)RBASE * 4;
  float* bwp = (float*)ws; ws += (size_t)RBASE * 4;
  int* smap  = (int*)ws;  ws += (size_t)2 * T_TOK * 4;
  int* seg   = (int*)ws;  ws += 16 * 4;
  int* segc  = (int*)ws;

  k_cvt_wgup<<<dim3(32, 32, NE), dim3(32, 8), 0, stream>>>(wgu, wsg, wgupT);
  k_cvt_wdown<<<dim3(32, 16, NE), dim3(32, 8), 0, stream>>>(wdn, wsd, wdT);
  k_router<<<T_TOK / 4, 256, 0, stream>>>(x, wg, xb, eidx, wt);
  k_scatter<<<1, 512, 0, stream>>>(eidx, wt, btok, bwp, smap, seg, segc);
  k_gemm_gu<<<(NSLOT / BM) * 8, 256, 0, stream>>>(
      xb, wgupT, seg, segc, btok, bwp, actb);
  k_gemm_down<<<(NSLOT / BM) * 8, 256, 0, stream>>>(actb, wdT, seg, segc, tmp);
  k_combine<<<(T_TOK * HID / 8) / 256, 256, 0, stream>>>(tmp, smap, out);
}

// Round 5
// 259.027 us; speedup vs baseline: 1.0320x; 1.0320x over previous
//
#include <hip/hip_runtime.h>
#include <hip/hip_bf16.h>
#include <cstdint>

#define T_TOK 8192
#define HID   1024
#define NE    9      // 8 routed experts + 1 shared
#define ISZ   512
#define RBASE 17408  // routed slot space: 16384 + 8*128 padding; shared rows at [RBASE, RBASE+8192)
#define NSLOT (RBASE + T_TOK)

#define BM 128
#define BN 128
#define BK 32
#define NROWB (NSLOT / BM)   // 200

typedef unsigned short u16;
typedef unsigned int   u32;
typedef __attribute__((ext_vector_type(8))) short short8;
typedef __attribute__((ext_vector_type(4))) float f32x4;

__device__ __forceinline__ u16 f2bf(float f) {
  u32 u = __builtin_bit_cast(u32, f);
  return (u16)((u + 0x7fffu + ((u >> 16) & 1u)) >> 16);
}
__device__ __forceinline__ float bf2f(u16 v) {
  return __builtin_bit_cast(float, (u32)v << 16);
}

#define STAGE(gp, lp) __builtin_amdgcn_global_load_lds( \
    (__attribute__((address_space(1))) u32*)(gp),       \
    (__attribute__((address_space(3))) u32*)(lp), 16, 0, 0)

// ---------------- weight conversions ----------------
__global__ void k_cvt_wgup(const float* __restrict__ wexp, const float* __restrict__ wsh,
                           u16* __restrict__ dst) {
  __shared__ float tile[32][33];
  const int e = blockIdx.z;
  const float* src = (e < 8) ? (wexp + (size_t)e * HID * 1024) : wsh;
  const int c0 = blockIdx.x * 32, h0 = blockIdx.y * 32;
  const int tx = threadIdx.x, ty = threadIdx.y;
  for (int i = ty; i < 32; i += 8)
    tile[i][tx] = src[(size_t)(h0 + i) * 1024 + c0 + tx];   // tile[h_loc][c_loc]
  __syncthreads();
  for (int j = ty; j < 32; j += 8) {
    int c = c0 + j;
    int i = (c < 512) ? c : (c - 512);
    int colp = ((i >> 4) * 32) + ((c < 512) ? 0 : 16) + (i & 15);
    dst[((size_t)e * 1024 + colp) * HID + h0 + tx] = f2bf(tile[tx][j]);
  }
}

__global__ void k_cvt_wdown(const float* __restrict__ wexp, const float* __restrict__ wsh,
                            u16* __restrict__ dst) {
  __shared__ float tile[32][33];
  const int e = blockIdx.z;
  const float* src = (e < 8) ? (wexp + (size_t)e * ISZ * HID) : wsh;
  const int h0 = blockIdx.x * 32, i0 = blockIdx.y * 32;
  const int tx = threadIdx.x, ty = threadIdx.y;
  for (int a = ty; a < 32; a += 8)
    tile[a][tx] = src[(size_t)(i0 + a) * HID + h0 + tx];    // tile[i_loc][h_loc]
  __syncthreads();
  for (int j = ty; j < 32; j += 8)
    dst[((size_t)e * HID + h0 + j) * ISZ + i0 + tx] = f2bf(tile[tx][j]);
}

// ---------------- router (fused x->bf16 conversion), no atomics ----------------
__global__ __launch_bounds__(256) void k_router(
    const float* __restrict__ x, const float* __restrict__ wg,
    u16* __restrict__ xb, int* __restrict__ eidx, float2* __restrict__ wts) {
  const int t = blockIdx.x * 4 + (threadIdx.x >> 6);
  const int l = threadIdx.x & 63;
  float a[8] = {0, 0, 0, 0, 0, 0, 0, 0};
  const float* xr = x + (size_t)t * HID;
  u16* xbr = xb + (size_t)t * HID;
#pragma unroll
  for (int j = 0; j < HID / 64; ++j) {
    const int h = j * 64 + l;
    const float xv = xr[h];
    xbr[h] = f2bf(xv);
    const float4 w0 = *(const float4*)&wg[h * 8];
    const float4 w1 = *(const float4*)&wg[h * 8 + 4];
    a[0] += xv * w0.x; a[1] += xv * w0.y; a[2] += xv * w0.z; a[3] += xv * w0.w;
    a[4] += xv * w1.x; a[5] += xv * w1.y; a[6] += xv * w1.z; a[7] += xv * w1.w;
  }
#pragma unroll
  for (int off = 32; off >= 1; off >>= 1) {
#pragma unroll
    for (int e2 = 0; e2 < 8; ++e2) a[e2] += __shfl_xor(a[e2], off);
  }
  if (l == 0) {
    int ia = 0;
#pragma unroll
    for (int e2 = 1; e2 < 8; ++e2) if (a[e2] > a[ia]) ia = e2;
    int ib = (ia == 0) ? 1 : 0;
#pragma unroll
    for (int e2 = 0; e2 < 8; ++e2) if (e2 != ia && a[e2] > a[ib]) ib = e2;
    float wa = 1.f / (1.f + expf(a[ib] - a[ia]));  // renormalized softmax top-2
    eidx[t] = ia | (ib << 8);
    wts[t] = make_float2(wa, 1.f - wa);
  }
}

// ---------------- deterministic counting scatter ----------------
__global__ __launch_bounds__(512) void k_scatter(
    const int* __restrict__ eidx, const float2* __restrict__ wts,
    int* __restrict__ btok, float* __restrict__ bw, int* __restrict__ slotmap,
    int* __restrict__ seg, int* __restrict__ segcnt) {
  __shared__ int cnt_s[8];
  __shared__ int goff_s[9];
  const int e = threadIdx.x >> 6;
  const int l = threadIdx.x & 63;

  int c1 = 0;
  for (int c = 0; c < T_TOK / 64; ++c) {
    int v = eidx[c * 64 + l];
    c1 += __popcll(__ballot((v & 255) == e)) + __popcll(__ballot(((v >> 8) & 255) == e));
  }
  if (l == 0) cnt_s[e] = c1;
  __syncthreads();
  if (threadIdx.x == 0) {
    int off = 0;
    for (int k = 0; k < 8; ++k) { goff_s[k] = off; off += (cnt_s[k] + 127) & ~127; }
    goff_s[8] = off;
  }
  __syncthreads();
  const int base0 = goff_s[e];
  const int cnt_e = cnt_s[e];
  const unsigned long long below = (l == 63) ? ~0ull >> 1 : ((1ull << l) - 1);

  int base = base0;
  for (int c = 0; c < T_TOK / 64; ++c) {
    const int t = c * 64 + l;
    const int v = eidx[t];
    const float2 wv = wts[t];
    const unsigned long long ma = __ballot((v & 255) == e);
    const unsigned long long mb = __ballot(((v >> 8) & 255) == e);
    if ((v & 255) == e) {
      int s = base + __popcll(ma & below);
      btok[s] = t; bw[s] = wv.x; slotmap[2 * t] = s;
    }
    if (((v >> 8) & 255) == e) {
      int s = base + __popcll(ma) + __popcll(mb & below);
      btok[s] = t; bw[s] = wv.y; slotmap[2 * t + 1] = s;
    }
    base += __popcll(ma) + __popcll(mb);
  }
  for (int p = cnt_e + l; p < ((cnt_e + 127) & ~127); p += 64) {
    btok[base0 + p] = 0; bw[base0 + p] = 0.f;
  }
  if (threadIdx.x < 9) seg[threadIdx.x] = goff_s[threadIdx.x];
  if (threadIdx.x < 8) segcnt[threadIdx.x] = cnt_s[threadIdx.x];
}

// ---------------- segment lookup ----------------
__device__ __forceinline__ bool seg_lookup(const int* __restrict__ seg,
                                           const int* __restrict__ segcnt,
                                           int brow, int& e) {
  if (brow >= RBASE) { e = 8; return true; }
  if (brow >= seg[8]) return false;
  e = 0;
#pragma unroll
  for (int k = 1; k < 8; ++k) if (brow >= seg[k]) e = k;
  return brow < seg[e] + segcnt[e];
}

// ---------------- GEMM1: act[slot] = silu(g)*u * w  (pipelined, dbuf) ----------
__global__ __launch_bounds__(256) void k_gemm_gu(
    const u16* __restrict__ xb,     // [T][H] bf16
    const u16* __restrict__ wgupT,  // [NE][1024][H] bf16 (B^T, interleaved cols)
    const int* __restrict__ seg, const int* __restrict__ segcnt,
    const int* __restrict__ btok, const float* __restrict__ bw,
    u16* __restrict__ act)          // [NSLOT][ISZ] bf16 (pre-scaled)
{
  const int bid = blockIdx.x;
  const int brow = (bid % NROWB) * BM;     // row-block fastest
  const int bcol_blk = bid / NROWB;
  int e;
  if (!seg_lookup(seg, segcnt, brow, e)) return;

  __shared__ __align__(16) u16 As[2][BM * BK];
  __shared__ __align__(16) u16 Bs[2][BN * BK];
  __shared__ float cws[BM];

  const int tid = threadIdx.x;
  const int w = tid >> 6, l = tid & 63;
  const int bcol = bcol_blk * BN;

  if (tid < BM) cws[tid] = (e < 8) ? bw[brow + tid] : 1.f;

  const int sub = l >> 2;        // row within 16-row chunk
  const int kc  = (l & 3) * 8;   // k element offset

  const int gs0 = brow + (w * 2 + 0) * 16 + sub;
  const int gs1 = brow + (w * 2 + 1) * 16 + sub;
  const int t0 = (e < 8) ? btok[gs0] : (gs0 - RBASE);
  const int t1 = (e < 8) ? btok[gs1] : (gs1 - RBASE);

  const u16* ga0 = xb + (size_t)t0 * HID + kc;
  const u16* ga1 = xb + (size_t)t1 * HID + kc;
  const u16* gb0 = wgupT + ((size_t)e * 1024 + bcol + (w * 2 + 0) * 16 + sub) * HID + kc;
  const u16* gb1 = wgupT + ((size_t)e * 1024 + bcol + (w * 2 + 1) * 16 + sub) * HID + kc;

  u16* la0 = &As[0][(w * 2 + 0) * 16 * BK];
  u16* la1 = &As[0][(w * 2 + 1) * 16 * BK];
  u16* lb0 = &Bs[0][(w * 2 + 0) * 16 * BK];
  u16* lb1 = &Bs[0][(w * 2 + 1) * 16 * BK];

  const int wm = w >> 1, wn = w & 1;
  const int fr = l & 15, fg = l >> 4;

  f32x4 acc[4][4];
#pragma unroll
  for (int m = 0; m < 4; ++m)
#pragma unroll
    for (int n = 0; n < 4; ++n) acc[m][n] = (f32x4){0.f, 0.f, 0.f, 0.f};

  // prologue: stage tile 0 into buf 0
  STAGE(ga0, la0);
  STAGE(ga1, la1);
  STAGE(gb0, lb0);
  STAGE(gb1, lb1);
  asm volatile("s_waitcnt vmcnt(0)" ::: "memory");
  __builtin_amdgcn_s_barrier();

  int cur = 0;
  const int NKT = HID / BK;
  for (int kt = 0; kt < NKT; ++kt) {
    if (kt + 1 < NKT) {           // prefetch next tile into buf^1 (no wait)
      const int ko = (kt + 1) * BK;
      const int oa = (cur ^ 1) * (BM * BK);
      const int ob = (cur ^ 1) * (BN * BK);
      STAGE(ga0 + ko, la0 + oa);
      STAGE(ga1 + ko, la1 + oa);
      STAGE(gb0 + ko, lb0 + ob);
      STAGE(gb1 + ko, lb1 + ob);
    }
    const u16* Ab = &As[cur][0];
    const u16* Bb = &Bs[cur][0];
    short8 af[4], bfr[4];
#pragma unroll
    for (int m = 0; m < 4; ++m)
      af[m] = *(const short8*)&Ab[(wm * 64 + m * 16 + fr) * BK + fg * 8];
#pragma unroll
    for (int n = 0; n < 4; ++n)
      bfr[n] = *(const short8*)&Bb[(wn * 64 + n * 16 + fr) * BK + fg * 8];
    __builtin_amdgcn_s_setprio(1);
#pragma unroll
    for (int m = 0; m < 4; ++m)
#pragma unroll
      for (int n = 0; n < 4; ++n)
        acc[m][n] = __builtin_amdgcn_mfma_f32_16x16x32_bf16(af[m], bfr[n], acc[m][n], 0, 0, 0);
    __builtin_amdgcn_s_setprio(0);
    asm volatile("s_waitcnt vmcnt(0)" ::: "memory");
    __builtin_amdgcn_s_barrier();
    cur ^= 1;
  }

#pragma unroll
  for (int m = 0; m < 4; ++m) {
#pragma unroll
    for (int p = 0; p < 2; ++p) {
      f32x4 g = acc[m][2 * p], u = acc[m][2 * p + 1];
      const int col = (bcol_blk * 4 + wn * 2 + p) * 16 + fr;
#pragma unroll
      for (int r = 0; r < 4; ++r) {
        const int row_l = wm * 64 + m * 16 + fg * 4 + r;
        float gate = g[r], u2 = u[r];
        float s = gate / (1.f + __expf(-gate));
        act[(size_t)(brow + row_l) * ISZ + col] = f2bf(s * u2 * cws[row_l]);
      }
    }
  }
}

// ---------------- GEMM2 (unified): tmp[slot] = act[slot] @ wdT[e]  (pipelined) ---
__global__ __launch_bounds__(256) void k_gemm_down(
    const u16* __restrict__ act, const u16* __restrict__ wdT,
    const int* __restrict__ seg, const int* __restrict__ segcnt,
    u16* __restrict__ tmp) {
  const int bid = blockIdx.x;
  const int brow = (bid % NROWB) * BM;
  const int bcol_blk = bid / NROWB;
  int e;
  if (!seg_lookup(seg, segcnt, brow, e)) return;
  const int bcol = bcol_blk * BN;

  __shared__ __align__(16) u16 As[2][BM * BK];
  __shared__ __align__(16) u16 Bs[2][BN * BK];

  const int tid = threadIdx.x;
  const int w = tid >> 6, l = tid & 63;
  const int sub = l >> 2;
  const int kc  = (l & 3) * 8;

  const u16* pa0 = act + (size_t)(brow + (w * 2 + 0) * 16 + sub) * ISZ + kc;
  const u16* pa1 = act + (size_t)(brow + (w * 2 + 1) * 16 + sub) * ISZ + kc;
  const u16* pb0 = wdT + ((size_t)e * HID + bcol + (w * 2 + 0) * 16 + sub) * ISZ + kc;
  const u16* pb1 = wdT + ((size_t)e * HID + bcol + (w * 2 + 1) * 16 + sub) * ISZ + kc;

  u16* la0 = &As[0][(w * 2 + 0) * 16 * BK];
  u16* la1 = &As[0][(w * 2 + 1) * 16 * BK];
  u16* lb0 = &Bs[0][(w * 2 + 0) * 16 * BK];
  u16* lb1 = &Bs[0][(w * 2 + 1) * 16 * BK];

  const int wm = w >> 1, wn = w & 1;
  const int fr = l & 15, fg = l >> 4;

  f32x4 acc[4][4];
#pragma unroll
  for (int m = 0; m < 4; ++m)
#pragma unroll
    for (int n = 0; n < 4; ++n) acc[m][n] = (f32x4){0.f, 0.f, 0.f, 0.f};

  STAGE(pa0, la0);
  STAGE(pa1, la1);
  STAGE(pb0, lb0);
  STAGE(pb1, lb1);
  asm volatile("s_waitcnt vmcnt(0)" ::: "memory");
  __builtin_amdgcn_s_barrier();

  int cur = 0;
  const int NKT = ISZ / BK;
  for (int kt = 0; kt < NKT; ++kt) {
    if (kt + 1 < NKT) {
      const int ko = (kt + 1) * BK;
      const int oa = (cur ^ 1) * (BM * BK);
      const int ob = (cur ^ 1) * (BN * BK);
      STAGE(pa0 + ko, la0 + oa);
      STAGE(pa1 + ko, la1 + oa);
      STAGE(pb0 + ko, lb0 + ob);
      STAGE(pb1 + ko, lb1 + ob);
    }
    const u16* Ab = &As[cur][0];
    const u16* Bb = &Bs[cur][0];
    short8 af[4], bfr[4];
#pragma unroll
    for (int m = 0; m < 4; ++m)
      af[m] = *(const short8*)&Ab[(wm * 64 + m * 16 + fr) * BK + fg * 8];
#pragma unroll
    for (int n = 0; n < 4; ++n)
      bfr[n] = *(const short8*)&Bb[(wn * 64 + n * 16 + fr) * BK + fg * 8];
    __builtin_amdgcn_s_setprio(1);
#pragma unroll
    for (int m = 0; m < 4; ++m)
#pragma unroll
      for (int n = 0; n < 4; ++n)
        acc[m][n] = __builtin_amdgcn_mfma_f32_16x16x32_bf16(af[m], bfr[n], acc[m][n], 0, 0, 0);
    __builtin_amdgcn_s_setprio(0);
    asm volatile("s_waitcnt vmcnt(0)" ::: "memory");
    __builtin_amdgcn_s_barrier();
    cur ^= 1;
  }

#pragma unroll
  for (int m = 0; m < 4; ++m) {
#pragma unroll
    for (int r = 0; r < 4; ++r) {
      const int row = brow + wm * 64 + m * 16 + fg * 4 + r;
#pragma unroll
      for (int n = 0; n < 4; ++n) {
        const int col = bcol + wn * 64 + n * 16 + fr;
        tmp[(size_t)row * HID + col] = f2bf(acc[m][n][r]);
      }
    }
  }
}

// ---------------- combine: out[t] = tmp[sh] + tmp[s0] + tmp[s1]  (pure write) ----
__global__ __launch_bounds__(256) void k_combine(
    const u16* __restrict__ tmp, const int* __restrict__ slotmap,
    float* __restrict__ out) {
  const int idx = blockIdx.x * 256 + threadIdx.x;
  const int t = idx >> 7;
  const int c = (idx & 127) << 3;
  const int s0 = slotmap[2 * t], s1 = slotmap[2 * t + 1];
  const short8 a = *(const short8*)(tmp + (size_t)s0 * HID + c);
  const short8 b = *(const short8*)(tmp + (size_t)s1 * HID + c);
  const short8 s = *(const short8*)(tmp + (size_t)(RBASE + t) * HID + c);
  float r[8];
#pragma unroll
  for (int j = 0; j < 8; ++j)
    r[j] = bf2f((u16)s[j]) + bf2f((u16)a[j]) + bf2f((u16)b[j]);
  float* po = out + (size_t)t * HID + c;
  *(float4*)po       = make_float4(r[0], r[1], r[2], r[3]);
  *(float4*)(po + 4) = make_float4(r[4], r[5], r[6], r[7]);
}

// ---------------- launch ----------------
extern "C" void kernel_launch(void* const* d_in, const int* in_sizes, int n_in,
                              void* d_out, int out_size, void* d_ws, size_t ws_size,
                              hipStream_t stream) {
  const float* x   = (const float*)d_in[0];
  const float* wg  = (const float*)d_in[1];
  const float* wgu = (const float*)d_in[2];
  const float* wdn = (const float*)d_in[3];
  const float* wsg = (const float*)d_in[4];
  const float* wsd = (const float*)d_in[5];
  float* out = (float*)d_out;

  char* ws = (char*)d_ws;
  u16* xb    = (u16*)ws;  ws += (size_t)T_TOK * HID * 2;
  u16* wgupT = (u16*)ws;  ws += (size_t)NE * 1024 * HID * 2;
  u16* wdT   = (u16*)ws;  ws += (size_t)NE * HID * ISZ * 2;
  u16* actb  = (u16*)ws;  ws += (size_t)NSLOT * ISZ * 2;
  u16* tmp   = (u16*)ws;  ws += (size_t)NSLOT * HID * 2;
  int* eidx  = (int*)ws;  ws += (size_t)T_TOK * 4;
  float2* wt = (float2*)ws; ws += (size_t)T_TOK * 8;
  int* btok  = (int*)ws;  ws += (size_t)RBASE * 4;
  float* bwp = (float*)ws; ws += (size_t)RBASE * 4;
  int* smap  = (int*)ws;  ws += (size_t)2 * T_TOK * 4;
  int* seg   = (int*)ws;  ws += 16 * 4;
  int* segc  = (int*)ws;

  k_cvt_wgup<<<dim3(32, 32, NE), dim3(32, 8), 0, stream>>>(wgu, wsg, wgupT);
  k_cvt_wdown<<<dim3(32, 16, NE), dim3(32, 8), 0, stream>>>(wdn, wsd, wdT);
  k_router<<<T_TOK / 4, 256, 0, stream>>>(x, wg, xb, eidx, wt);
  k_scatter<<<1, 512, 0, stream>>>(eidx, wt, btok, bwp, smap, seg, segc);
  k_gemm_gu<<<NROWB * 8, 256, 0, stream>>>(
      xb, wgupT, seg, segc, btok, bwp, actb);
  k_gemm_down<<<NROWB * 8, 256, 0, stream>>>(actb, wdT, seg, segc, tmp);
  k_combine<<<(T_TOK * HID / 8) / 256, 256, 0, stream>>>(tmp, smap, out);
}